// Round 24
// baseline (234.709 us; speedup 1.0000x reference)
//
#include <hip/hip_runtime.h>
#include <hip/hip_bf16.h>

#define EMB 64
#define XCOLS 20
#define NSYMP 15
#define BSH 7
#define BSZ 128          // nodes per bucket (1<<BSH)
#define MAXNB 1024       // supports N <= 131072
#define PCHUNK 4096
#define TROWS 51         // 4 birth + 2 gender + 45 symp rows
#define CAP 2560         // fixed edge capacity per bucket (~11 sigma margin)
#define SCAP (CAP + BSZ) // slot capacity per bucket incl. self-loops

typedef float sf16 __attribute__((ext_vector_type(16)));

// ---------------- table transform (+ zero bcursor; saves a memset dispatch) --
__global__ void transform_kernel(const float* __restrict__ bt,
                                 const float* __restrict__ gt,
                                 const float* __restrict__ st,
                                 const float* __restrict__ Wl,
                                 const float* __restrict__ Wr,
                                 float* __restrict__ tL, float* __restrict__ tR,
                                 int* __restrict__ bcursor) {
    __shared__ float row[EMB];
    int r = blockIdx.x;          // 0..50
    int d = threadIdx.x;         // 64 threads
    int gi = r * 64 + d;
    if (gi < MAXNB) bcursor[gi] = 0;
    const float* src = (r < 4) ? (bt + r * EMB)
                     : (r < 6) ? (gt + (r - 4) * EMB)
                               : (st + (r - 6) * EMB);
    row[d] = src[d];
    __syncthreads();
    float aL = 0.f, aR = 0.f;
#pragma unroll
    for (int k = 0; k < EMB; ++k) {
        float h = row[k];
        aL = fmaf(h, Wl[k * EMB + d], aL);
        aR = fmaf(h, Wr[k * EMB + d], aR);
    }
    tL[r * EMB + d] = aL;
    tR[r * EMB + d] = aR;
}

// ---------------- embed + partition (block-role split, EMBED FIRST) --------
// R23 post-mortem: partition was pinned at ~70us regardless of per-block
// optimizations -> scheduling-skew model: partition blocks [0,391) clustered
// on the first ~49 CUs, running ~8 long blocks serially while other CUs
// drained short embed blocks and idled. Putting the 12.5K short embed blocks
// FIRST floods all CUs; the 391 partition blocks then spread ~1.5/CU.
__global__ void partition_embed_kernel(const int* __restrict__ ei, int* __restrict__ bcursor,
                                       int* __restrict__ epart, int E, int NB, int EB,
                                       const int* __restrict__ x,
                                       const float* __restrict__ tL,
                                       const float* __restrict__ tR,
                                       const float* __restrict__ bl,
                                       const float* __restrict__ br,
                                       float* __restrict__ outL, float* __restrict__ outR,
                                       int N) {
    __shared__ int lh8[8][MAXNB];  // partition role (32 KB)
    __shared__ int xs[8 * XCOLS];  // embed role (640 B)
    if (blockIdx.x < EB) {
        // ---- embedgemm role: 8 nodes per 512-thread block ----
        int bid = blockIdx.x;
        int node = bid * 8 + (threadIdx.x >> 6);
        int d = threadIdx.x & 63;
        if (threadIdx.x < 8 * XCOLS) {
            int n2 = bid * 8 + threadIdx.x / XCOLS;
            xs[threadIdx.x] = (n2 < N) ? x[(size_t)bid * 8 * XCOLS + threadIdx.x] : 0;
        }
        __syncthreads();
        if (node >= N) return;
        const int* xr = &xs[(threadIdx.x >> 6) * XCOLS];
        int rbi = xr[1] + 2 * xr[2] + 3 * xr[3];   // birth row 0..3
        int rg = 4 + xr[4];                        // gender row 4..5
        float fL = 0.f, fR = 0.f;
#pragma unroll
        for (int j = 0; j < NSYMP; ++j) {
            int row = 6 + j * 3 + xr[5 + j];
            fL += tL[row * EMB + d];
            fR += tR[row * EMB + d];
        }
        float aL = (tL[rbi * EMB + d] + tL[rg * EMB + d] + fL * (1.f / 15.f)) * (1.f / 3.f) + bl[d];
        float aR = (tR[rbi * EMB + d] + tR[rg * EMB + d] + fR * (1.f / 15.f)) * (1.f / 3.f) + br[d];
        outL[node * EMB + d] = aL;
        outR[node * EMB + d] = aR;
        return;
    }
    // ---- partition role ----
    int pb = blockIdx.x - EB;
    int w = threadIdx.x >> 6;      // wave 0..7
    for (int j = threadIdx.x; j < 8 * MAXNB; j += 512) ((int*)lh8)[j] = 0;
    __syncthreads();
    int base = pb * PCHUNK;
    int end = min(E, base + PCHUNK);
    for (int i = base + threadIdx.x; i < end; i += 512)
        atomicAdd(&lh8[w][ei[E + i] >> BSH], 1);
    __syncthreads();
    for (int j = threadIdx.x; j < NB; j += 512) {
        int c[8];
        int tot = 0;
#pragma unroll
        for (int k = 0; k < 8; ++k) { c[k] = lh8[k][j]; tot += c[k]; }
        int rb = tot ? (j * CAP + atomicAdd(&bcursor[j], tot)) : 0;
#pragma unroll
        for (int k = 0; k < 8; ++k) { lh8[k][j] = rb; rb += c[k]; }
    }
    __syncthreads();
    for (int i = base + threadIdx.x; i < end; i += 512) {
        int dst = ei[E + i];
        int src = ei[i];
        int slot = atomicAdd(&lh8[w][dst >> BSH], 1);
        epart[slot] = (src << BSH) | (dst & (BSZ - 1));
    }
}

// ---------------- dual GEMM v8: scalar-cache h broadcast + register weights --
__global__ __launch_bounds__(256, 3)
void gemm_dual_kernel(const float* __restrict__ h,
                      const float* __restrict__ Wl, const float* __restrict__ bl,
                      const float* __restrict__ Wr, const float* __restrict__ br,
                      float* __restrict__ outL, float* __restrict__ outR, int N) {
    int lane = threadIdx.x & 63;
    int wv = threadIdx.x >> 6;
    float wl[EMB], wr[EMB];
#pragma unroll
    for (int k = 0; k < EMB; ++k) {
        wl[k] = Wl[k * EMB + lane];
        wr[k] = Wr[k * EMB + lane];
    }
    float blv = bl[lane], brv = br[lane];
    int stride = gridDim.x * 4;
    for (int node = blockIdx.x * 4 + wv; node < N; node += stride) {
        int un = __builtin_amdgcn_readfirstlane(node);
        const float* hrow = h + (size_t)un * EMB;
        sf16 va, vb, vc, vd;
        asm volatile("s_load_dwordx16 %0, %1, 0x0"  : "=s"(va) : "s"(hrow));
        asm volatile("s_load_dwordx16 %0, %1, 0x40" : "=s"(vb) : "s"(hrow));
        asm volatile("s_load_dwordx16 %0, %1, 0x80" : "=s"(vc) : "s"(hrow));
        asm volatile("s_load_dwordx16 %0, %1, 0xc0" : "=s"(vd) : "s"(hrow));
        asm volatile("s_waitcnt lgkmcnt(0)" ::: "memory");
        __builtin_amdgcn_sched_barrier(0);
        float l0 = blv, l1 = 0.f, r0 = brv, r1 = 0.f;
#pragma unroll
        for (int k = 0; k < 16; ++k) {
            l0 = fmaf(va[k], wl[k], l0);
            r0 = fmaf(va[k], wr[k], r0);
            l1 = fmaf(vb[k], wl[16 + k], l1);
            r1 = fmaf(vb[k], wr[16 + k], r1);
            l0 = fmaf(vc[k], wl[32 + k], l0);
            r0 = fmaf(vc[k], wr[32 + k], r0);
            l1 = fmaf(vd[k], wl[48 + k], l1);
            r1 = fmaf(vd[k], wr[48 + k], r1);
        }
        outL[(size_t)node * EMB + lane] = l0 + l1;
        outR[(size_t)node * EMB + lane] = r0 + r1;
    }
}

// finalize: bucket b's edges at epart[b*CAP .. b*CAP+cnt); slots for its 128
// nodes at ssrc[b*SCAP ..]. Writes offs (start) and eoffs (end) per node.
__global__ void finalize_kernel(const int* __restrict__ epart, const int* __restrict__ bcursor,
                                int* __restrict__ offs, int* __restrict__ eoffs,
                                int* __restrict__ ssrc, int N, int S /* pad start */) {
    __shared__ int deg4[4][BSZ];
    __shared__ int pos[BSZ];
    __shared__ int cur4[4][BSZ];
    int b = blockIdx.x;
    int t = threadIdx.x;
    int w = t >> 6;
    int n0 = b << BSH;
    int cnt = bcursor[b];
    int r0 = b * CAP, r1 = r0 + cnt;
    int sbase = b * SCAP;
    if (b == 0 && t < 128) ssrc[S + t] = 0;
    ((int*)deg4)[t] = 0;
    ((int*)deg4)[t + 256] = 0;
    __syncthreads();
    for (int e = r0 + t; e < r1; e += 256)
        atomicAdd(&deg4[w][epart[e] & (BSZ - 1)], 1);
    __syncthreads();
    int d0 = 0, d1 = 0, d2 = 0, sum = 0;
    if (t < BSZ) {
        d0 = deg4[0][t]; d1 = deg4[1][t]; d2 = deg4[2][t];
        sum = d0 + d1 + d2 + deg4[3][t];
        pos[t] = sum;
    }
    __syncthreads();
    for (int off = 1; off < BSZ; off <<= 1) {
        int v = (t < BSZ && t >= off) ? pos[t - off] : 0;
        __syncthreads();
        if (t < BSZ) pos[t] += v;
        __syncthreads();
    }
    if (t < BSZ) {
        int node = n0 + t;
        int base = sbase + (pos[t] - sum) + t;   // edges-before + self-slots-before
        if (node < N) {
            offs[node] = base;
            eoffs[node] = base + 1 + sum;        // end of this node's range
            ssrc[base] = node;                   // self-loop at slot 0
        }
        cur4[0][t] = base + 1;
        cur4[1][t] = base + 1 + d0;
        cur4[2][t] = base + 1 + d0 + d1;
        cur4[3][t] = base + 1 + d0 + d1 + d2;
    }
    __syncthreads();
    for (int e = r0 + t; e < r1; e += 256) {
        int v = epart[e];
        int s = atomicAdd(&cur4[w][v & (BSZ - 1)], 1);
        ssrc[s] = v >> BSH;
    }
}

// ---------------- DPP cross-lane add (VALU pipe; compiler handles hazards) --
template <int CTRL>
__device__ __forceinline__ float dpp_add(float v) {
    union { float f; int i; } u, r;
    u.f = v;
    r.i = __builtin_amdgcn_update_dpp(0, u.i, CTRL, 0xF, 0xF, true);
    return v + r.f;
}

// ---------------- GATv2 layer: 8 edges per wave iteration, pipelined --------
// R17 lesson: tail-slot index CLAMP to `wid` (L1-hot own row) is load-bearing.
template <int L>
__global__ void gat_kernel(const float* __restrict__ xl, const float* __restrict__ xr,
                           const int* __restrict__ offs, const int* __restrict__ eoffs,
                           const int* __restrict__ ssrc,
                           const float* __restrict__ att, const float* __restrict__ bias,
                           const float* __restrict__ linW, const float* __restrict__ linb,
                           float* __restrict__ out, int N) {
    int wid = blockIdx.x * 4 + (threadIdx.x >> 6);
    int lane = threadIdx.x & 63;
    if (wid >= N) return;
    int grp = lane >> 4;          // edge slot within the 4-wide half-batch
    int li = lane & 15;           // float4 channel slot
    unsigned cb = (unsigned)li << 2;

    const float LOG2E = 1.4426950408889634f;
    float4 att4 = *(const float4*)(att + cb);
    att4.x *= LOG2E; att4.y *= LOG2E; att4.z *= LOG2E; att4.w *= LOG2E;
    float4 bias4 = *(const float4*)(bias + cb);
    unsigned rb = (unsigned)wid << 6;
    float4 xr4 = *(const float4*)(xr + rb + cb);

    int e0 = offs[wid], e1 = eoffs[wid];
    int e1a = e1 - grp;           // t+grp < e1    <=>  t < e1a
    int e1b = e1 - 4 - grp;       // t+4+grp < e1  <=>  t < e1b

    float s = 0.f;
    float4 acc = {0.f, 0.f, 0.f, 0.f};

    // prologue (allocated pad -> unconditional loads OK; clamp to hot own-row)
    unsigned sA = (unsigned)ssrc[e0 + grp];
    unsigned sB = (unsigned)ssrc[e0 + 4 + grp];
    sA = (e0 < e1a) ? sA : (unsigned)wid;
    sB = (e0 < e1b) ? sB : (unsigned)wid;

    for (int t = e0; t < e1; t += 8) {
        float4 a = *(const float4*)(xl + (sA << 6) + cb);
        float4 b = *(const float4*)(xl + (sB << 6) + cb);
        int tn = t + 8;
        unsigned nA = (unsigned)ssrc[tn + grp];
        unsigned nB = (unsigned)ssrc[tn + 4 + grp];
        nA = (tn < e1a) ? nA : (unsigned)wid;
        nB = (tn < e1b) ? nB : (unsigned)wid;
        bool vA = t < e1a;
        bool vB = t < e1b;

        float ux = a.x + xr4.x; ux = fmaxf(ux, 0.2f * ux);
        float uy = a.y + xr4.y; uy = fmaxf(uy, 0.2f * uy);
        float uz = a.z + xr4.z; uz = fmaxf(uz, 0.2f * uz);
        float uw = a.w + xr4.w; uw = fmaxf(uw, 0.2f * uw);
        float pa = att4.x * ux + att4.y * uy + att4.z * uz + att4.w * uw;
        pa = dpp_add<0xB1>(pa);
        pa = dpp_add<0x4E>(pa);
        if (L == 2) {
            pa = dpp_add<0x141>(pa);
            pa = dpp_add<0x140>(pa);
        }
        float pA = exp2f(pa);
        pA = vA ? pA : 0.f;
        s += pA;
        acc.x += pA * a.x; acc.y += pA * a.y; acc.z += pA * a.z; acc.w += pA * a.w;

        float vx = b.x + xr4.x; vx = fmaxf(vx, 0.2f * vx);
        float vy = b.y + xr4.y; vy = fmaxf(vy, 0.2f * vy);
        float vz = b.z + xr4.z; vz = fmaxf(vz, 0.2f * vz);
        float vw = b.w + xr4.w; vw = fmaxf(vw, 0.2f * vw);
        float pb = att4.x * vx + att4.y * vy + att4.z * vz + att4.w * vw;
        pb = dpp_add<0xB1>(pb);
        pb = dpp_add<0x4E>(pb);
        if (L == 2) {
            pb = dpp_add<0x141>(pb);
            pb = dpp_add<0x140>(pb);
        }
        float pB = exp2f(pb);
        pB = vB ? pB : 0.f;
        s += pB;
        acc.x += pB * b.x; acc.y += pB * b.y; acc.z += pB * b.z; acc.w += pB * b.w;

        sA = nA; sB = nB;
    }

    // combine the 4 edge groups (once per node)
    s += __shfl_xor(s, 16); s += __shfl_xor(s, 32);
    acc.x += __shfl_xor(acc.x, 16); acc.x += __shfl_xor(acc.x, 32);
    acc.y += __shfl_xor(acc.y, 16); acc.y += __shfl_xor(acc.y, 32);
    acc.z += __shfl_xor(acc.z, 16); acc.z += __shfl_xor(acc.z, 32);
    acc.w += __shfl_xor(acc.w, 16); acc.w += __shfl_xor(acc.w, 32);

    float inv = 1.f / (s + 1e-16f);
    if (L == 1) {
        float4 val;
        val.x = acc.x * inv + bias4.x;
        val.y = acc.y * inv + bias4.y;
        val.z = acc.z * inv + bias4.z;
        val.w = acc.w * inv + bias4.w;
        val.x = (val.x > 0.f) ? val.x : (__expf(val.x) - 1.f);
        val.y = (val.y > 0.f) ? val.y : (__expf(val.y) - 1.f);
        val.z = (val.z > 0.f) ? val.z : (__expf(val.z) - 1.f);
        val.w = (val.w > 0.f) ? val.w : (__expf(val.w) - 1.f);
        if (grp == 0) *(float4*)(out + rb + cb) = val;
    } else {
        float4 lw = *(const float4*)(linW + cb);
        float r = (acc.x * inv + bias4.x) * lw.x + (acc.y * inv + bias4.y) * lw.y +
                  (acc.z * inv + bias4.z) * lw.z + (acc.w * inv + bias4.w) * lw.w;
        r = dpp_add<0xB1>(r);
        r = dpp_add<0x4E>(r);
        r = dpp_add<0x141>(r);
        r = dpp_add<0x140>(r);
        if (lane == 0) out[wid] = r + linb[0];
    }
}

extern "C" void kernel_launch(void* const* d_in, const int* in_sizes, int n_in,
                              void* d_out, int out_size, void* d_ws, size_t ws_size,
                              hipStream_t stream) {
    const int* x = (const int*)d_in[0];
    const int* ei = (const int*)d_in[1];          // int32 marshalled
    const float* birth_tab = (const float*)d_in[2];
    const float* gender_tab = (const float*)d_in[3];
    const float* symp_tab = (const float*)d_in[4];
    const float* Wl1 = (const float*)d_in[5];
    const float* bl1 = (const float*)d_in[6];
    const float* Wr1 = (const float*)d_in[7];
    const float* br1 = (const float*)d_in[8];
    const float* att1 = (const float*)d_in[9];
    const float* bias1 = (const float*)d_in[10];
    const float* Wl2 = (const float*)d_in[11];
    const float* bl2 = (const float*)d_in[12];
    const float* Wr2 = (const float*)d_in[13];
    const float* br2 = (const float*)d_in[14];
    const float* att2 = (const float*)d_in[15];
    const float* bias2 = (const float*)d_in[16];
    const float* linW = (const float*)d_in[17];
    const float* linb = (const float*)d_in[18];
    float* outp = (float*)d_out;

    int N = in_sizes[0] / XCOLS;   // 100000
    int E = in_sizes[1] / 2;       // 1600000
    int NB = (N + BSZ - 1) >> BSH; // 782

    char* p = (char*)d_ws;
    auto alloc = [&](size_t bytes) {
        void* r = (void*)p;
        p += (bytes + 255) & ~(size_t)255;
        return r;
    };
    float* h0 = (float*)alloc((size_t)N * EMB * 4);
    float* bufA = (float*)alloc((size_t)N * EMB * 4);
    float* bufB = (float*)alloc((size_t)N * EMB * 4);
    int* bcursor = (int*)alloc(MAXNB * 4);
    int* offs = (int*)alloc((size_t)N * 4);
    int* eoffs = (int*)alloc((size_t)N * 4);
    int* ssrc = (int*)alloc(((size_t)NB * SCAP + 256) * 4);
    float* tL = (float*)alloc((size_t)TROWS * EMB * 4);
    float* tR = (float*)alloc((size_t)TROWS * EMB * 4);
    int* epart = (int*)h0;   // alias: epart (NB*CAP = 8MB) dead before gat1 writes h0

    int ngrp = (N + 3) / 4;
    int ngrp8 = (N + 7) / 8;              // embed blocks (role 0)
    int PB = (E + PCHUNK - 1) / PCHUNK;   // 391 partition blocks (role 1)

    transform_kernel<<<TROWS, 64, 0, stream>>>(birth_tab, gender_tab, symp_tab,
                                               Wl1, Wr1, tL, tR, bcursor);
    // embed blocks first (flood all CUs), partition blocks trail (spread out)
    partition_embed_kernel<<<ngrp8 + PB, 512, 0, stream>>>(ei, bcursor, epart, E, NB, ngrp8,
                                                           x, tL, tR, bl1, br1,
                                                           bufA, bufB, N);
    finalize_kernel<<<NB, 256, 0, stream>>>(epart, bcursor, offs, eoffs, ssrc, N,
                                            NB * SCAP);

    // node pipeline
    gat_kernel<1><<<ngrp, 256, 0, stream>>>(bufA, bufB, offs, eoffs, ssrc, att1, bias1,
                                            nullptr, nullptr, h0, N);
    gemm_dual_kernel<<<768, 256, 0, stream>>>(h0, Wl2, bl2, Wr2, br2, bufA, bufB, N);
    gat_kernel<2><<<ngrp, 256, 0, stream>>>(bufA, bufB, offs, eoffs, ssrc, att2, bias2,
                                            linW, linb, outp, N);
}

// Round 25
// 229.582 us; speedup vs baseline: 1.0223x; 1.0223x over previous
//
#include <hip/hip_runtime.h>
#include <hip/hip_bf16.h>

#define EMB 64
#define XCOLS 20
#define NSYMP 15
#define BSH 7
#define BSZ 128          // nodes per bucket (1<<BSH)
#define MAXNB 1024       // supports N <= 131072
#define PCHUNK 4096
#define TROWS 51         // 4 birth + 2 gender + 45 symp rows
#define CAP 2560         // fixed edge capacity per bucket (~11 sigma margin)
#define SCAP (CAP + BSZ) // slot capacity per bucket incl. self-loops

typedef float sf16 __attribute__((ext_vector_type(16)));

// ---------------- table transform (+ zero bcursor; saves a memset dispatch) --
__global__ void transform_kernel(const float* __restrict__ bt,
                                 const float* __restrict__ gt,
                                 const float* __restrict__ st,
                                 const float* __restrict__ Wl,
                                 const float* __restrict__ Wr,
                                 float* __restrict__ tL, float* __restrict__ tR,
                                 int* __restrict__ bcursor) {
    __shared__ float row[EMB];
    int r = blockIdx.x;          // 0..50
    int d = threadIdx.x;         // 64 threads
    int gi = r * 64 + d;
    if (gi < MAXNB) bcursor[gi] = 0;
    const float* src = (r < 4) ? (bt + r * EMB)
                     : (r < 6) ? (gt + (r - 4) * EMB)
                               : (st + (r - 6) * EMB);
    row[d] = src[d];
    __syncthreads();
    float aL = 0.f, aR = 0.f;
#pragma unroll
    for (int k = 0; k < EMB; ++k) {
        float h = row[k];
        aL = fmaf(h, Wl[k * EMB + d], aL);
        aR = fmaf(h, Wr[k * EMB + d], aR);
    }
    tL[r * EMB + d] = aL;
    tR[r * EMB + d] = aR;
}

// ---------------- partition + fused embedgemm (block-role split, 512 thr) ---
// R24 lesson: embed-first scheduling regressed; partition-first (R23) is the
// measured best. Partition role is accepted as a ~70us structural floor
// (4 independent levers all null: chunk size, LDS contention, wave count,
// issue order).
__global__ void partition_embed_kernel(const int* __restrict__ ei, int* __restrict__ bcursor,
                                       int* __restrict__ epart, int E, int NB, int PB,
                                       const int* __restrict__ x,
                                       const float* __restrict__ tL,
                                       const float* __restrict__ tR,
                                       const float* __restrict__ bl,
                                       const float* __restrict__ br,
                                       float* __restrict__ outL, float* __restrict__ outR,
                                       int N) {
    __shared__ int lh8[8][MAXNB];  // partition role (32 KB)
    __shared__ int xs[8 * XCOLS];  // embed role (640 B)
    if (blockIdx.x >= PB) {
        // ---- embedgemm role: 8 nodes per 512-thread block ----
        int bid = blockIdx.x - PB;
        int node = bid * 8 + (threadIdx.x >> 6);
        int d = threadIdx.x & 63;
        if (threadIdx.x < 8 * XCOLS) {
            int n2 = bid * 8 + threadIdx.x / XCOLS;
            xs[threadIdx.x] = (n2 < N) ? x[(size_t)bid * 8 * XCOLS + threadIdx.x] : 0;
        }
        __syncthreads();
        if (node >= N) return;
        const int* xr = &xs[(threadIdx.x >> 6) * XCOLS];
        int rbi = xr[1] + 2 * xr[2] + 3 * xr[3];   // birth row 0..3
        int rg = 4 + xr[4];                        // gender row 4..5
        float fL = 0.f, fR = 0.f;
#pragma unroll
        for (int j = 0; j < NSYMP; ++j) {
            int row = 6 + j * 3 + xr[5 + j];
            fL += tL[row * EMB + d];
            fR += tR[row * EMB + d];
        }
        float aL = (tL[rbi * EMB + d] + tL[rg * EMB + d] + fL * (1.f / 15.f)) * (1.f / 3.f) + bl[d];
        float aR = (tR[rbi * EMB + d] + tR[rg * EMB + d] + fR * (1.f / 15.f)) * (1.f / 3.f) + br[d];
        outL[node * EMB + d] = aL;
        outR[node * EMB + d] = aR;
        return;
    }
    // ---- partition role ----
    int w = threadIdx.x >> 6;      // wave 0..7
    for (int j = threadIdx.x; j < 8 * MAXNB; j += 512) ((int*)lh8)[j] = 0;
    __syncthreads();
    int base = blockIdx.x * PCHUNK;
    int end = min(E, base + PCHUNK);
    for (int i = base + threadIdx.x; i < end; i += 512)
        atomicAdd(&lh8[w][ei[E + i] >> BSH], 1);
    __syncthreads();
    for (int j = threadIdx.x; j < NB; j += 512) {
        int c[8];
        int tot = 0;
#pragma unroll
        for (int k = 0; k < 8; ++k) { c[k] = lh8[k][j]; tot += c[k]; }
        int rb = tot ? (j * CAP + atomicAdd(&bcursor[j], tot)) : 0;
#pragma unroll
        for (int k = 0; k < 8; ++k) { lh8[k][j] = rb; rb += c[k]; }
    }
    __syncthreads();
    for (int i = base + threadIdx.x; i < end; i += 512) {
        int dst = ei[E + i];
        int src = ei[i];
        int slot = atomicAdd(&lh8[w][dst >> BSH], 1);
        epart[slot] = (src << BSH) | (dst & (BSZ - 1));
    }
}

// ---------------- dual GEMM v8: scalar-cache h broadcast + register weights --
__global__ __launch_bounds__(256, 3)
void gemm_dual_kernel(const float* __restrict__ h,
                      const float* __restrict__ Wl, const float* __restrict__ bl,
                      const float* __restrict__ Wr, const float* __restrict__ br,
                      float* __restrict__ outL, float* __restrict__ outR, int N) {
    int lane = threadIdx.x & 63;
    int wv = threadIdx.x >> 6;
    float wl[EMB], wr[EMB];
#pragma unroll
    for (int k = 0; k < EMB; ++k) {
        wl[k] = Wl[k * EMB + lane];
        wr[k] = Wr[k * EMB + lane];
    }
    float blv = bl[lane], brv = br[lane];
    int stride = gridDim.x * 4;
    for (int node = blockIdx.x * 4 + wv; node < N; node += stride) {
        int un = __builtin_amdgcn_readfirstlane(node);
        const float* hrow = h + (size_t)un * EMB;
        sf16 va, vb, vc, vd;
        asm volatile("s_load_dwordx16 %0, %1, 0x0"  : "=s"(va) : "s"(hrow));
        asm volatile("s_load_dwordx16 %0, %1, 0x40" : "=s"(vb) : "s"(hrow));
        asm volatile("s_load_dwordx16 %0, %1, 0x80" : "=s"(vc) : "s"(hrow));
        asm volatile("s_load_dwordx16 %0, %1, 0xc0" : "=s"(vd) : "s"(hrow));
        asm volatile("s_waitcnt lgkmcnt(0)" ::: "memory");
        __builtin_amdgcn_sched_barrier(0);
        float l0 = blv, l1 = 0.f, r0 = brv, r1 = 0.f;
#pragma unroll
        for (int k = 0; k < 16; ++k) {
            l0 = fmaf(va[k], wl[k], l0);
            r0 = fmaf(va[k], wr[k], r0);
            l1 = fmaf(vb[k], wl[16 + k], l1);
            r1 = fmaf(vb[k], wr[16 + k], r1);
            l0 = fmaf(vc[k], wl[32 + k], l0);
            r0 = fmaf(vc[k], wr[32 + k], r0);
            l1 = fmaf(vd[k], wl[48 + k], l1);
            r1 = fmaf(vd[k], wr[48 + k], r1);
        }
        outL[(size_t)node * EMB + lane] = l0 + l1;
        outR[(size_t)node * EMB + lane] = r0 + r1;
    }
}

// finalize: bucket b's edges at epart[b*CAP .. b*CAP+cnt); slots for its 128
// nodes at ssrc[b*SCAP ..]. Writes offs (start) and eoffs (end) per node.
__global__ void finalize_kernel(const int* __restrict__ epart, const int* __restrict__ bcursor,
                                int* __restrict__ offs, int* __restrict__ eoffs,
                                int* __restrict__ ssrc, int N, int S /* pad start */) {
    __shared__ int deg4[4][BSZ];
    __shared__ int pos[BSZ];
    __shared__ int cur4[4][BSZ];
    int b = blockIdx.x;
    int t = threadIdx.x;
    int w = t >> 6;
    int n0 = b << BSH;
    int cnt = bcursor[b];
    int r0 = b * CAP, r1 = r0 + cnt;
    int sbase = b * SCAP;
    if (b == 0 && t < 128) ssrc[S + t] = 0;
    ((int*)deg4)[t] = 0;
    ((int*)deg4)[t + 256] = 0;
    __syncthreads();
    for (int e = r0 + t; e < r1; e += 256)
        atomicAdd(&deg4[w][epart[e] & (BSZ - 1)], 1);
    __syncthreads();
    int d0 = 0, d1 = 0, d2 = 0, sum = 0;
    if (t < BSZ) {
        d0 = deg4[0][t]; d1 = deg4[1][t]; d2 = deg4[2][t];
        sum = d0 + d1 + d2 + deg4[3][t];
        pos[t] = sum;
    }
    __syncthreads();
    for (int off = 1; off < BSZ; off <<= 1) {
        int v = (t < BSZ && t >= off) ? pos[t - off] : 0;
        __syncthreads();
        if (t < BSZ) pos[t] += v;
        __syncthreads();
    }
    if (t < BSZ) {
        int node = n0 + t;
        int base = sbase + (pos[t] - sum) + t;   // edges-before + self-slots-before
        if (node < N) {
            offs[node] = base;
            eoffs[node] = base + 1 + sum;        // end of this node's range
            ssrc[base] = node;                   // self-loop at slot 0
        }
        cur4[0][t] = base + 1;
        cur4[1][t] = base + 1 + d0;
        cur4[2][t] = base + 1 + d0 + d1;
        cur4[3][t] = base + 1 + d0 + d1 + d2;
    }
    __syncthreads();
    for (int e = r0 + t; e < r1; e += 256) {
        int v = epart[e];
        int s = atomicAdd(&cur4[w][v & (BSZ - 1)], 1);
        ssrc[s] = v >> BSH;
    }
}

// ---------------- DPP cross-lane add (VALU pipe; compiler handles hazards) --
template <int CTRL>
__device__ __forceinline__ float dpp_add(float v) {
    union { float f; int i; } u, r;
    u.f = v;
    r.i = __builtin_amdgcn_update_dpp(0, u.i, CTRL, 0xF, 0xF, true);
    return v + r.f;
}

// ---------------- GATv2 layer: 8 edges per wave iteration, pipelined --------
// R25: leaky_relu(x,0.2) = 0.6x + 0.4|x| EXACTLY, and |x| is a free VOP3
// input modifier -> fold leaky into the att-dot: logit = sum attP*u + attN*|u|
// (4 add + 8 fma, was 4 add + 4 mul + 4 max + 4 fma). -25% of pre-reduce
// edge VALU. R17 lesson retained: tail-slot index CLAMP to `wid`.
template <int L>
__global__ void gat_kernel(const float* __restrict__ xl, const float* __restrict__ xr,
                           const int* __restrict__ offs, const int* __restrict__ eoffs,
                           const int* __restrict__ ssrc,
                           const float* __restrict__ att, const float* __restrict__ bias,
                           const float* __restrict__ linW, const float* __restrict__ linb,
                           float* __restrict__ out, int N) {
    int wid = blockIdx.x * 4 + (threadIdx.x >> 6);
    int lane = threadIdx.x & 63;
    if (wid >= N) return;
    int grp = lane >> 4;          // edge slot within the 4-wide half-batch
    int li = lane & 15;           // float4 channel slot
    unsigned cb = (unsigned)li << 2;

    const float LOG2E = 1.4426950408889634f;
    float4 att4 = *(const float4*)(att + cb);
    float4 attP, attN;
    attP.x = att4.x * (0.6f * LOG2E); attN.x = att4.x * (0.4f * LOG2E);
    attP.y = att4.y * (0.6f * LOG2E); attN.y = att4.y * (0.4f * LOG2E);
    attP.z = att4.z * (0.6f * LOG2E); attN.z = att4.z * (0.4f * LOG2E);
    attP.w = att4.w * (0.6f * LOG2E); attN.w = att4.w * (0.4f * LOG2E);
    float4 bias4 = *(const float4*)(bias + cb);
    unsigned rb = (unsigned)wid << 6;
    float4 xr4 = *(const float4*)(xr + rb + cb);

    int e0 = offs[wid], e1 = eoffs[wid];
    int e1a = e1 - grp;           // t+grp < e1    <=>  t < e1a
    int e1b = e1 - 4 - grp;       // t+4+grp < e1  <=>  t < e1b

    float s = 0.f;
    float4 acc = {0.f, 0.f, 0.f, 0.f};

    // prologue (allocated pad -> unconditional loads OK; clamp to hot own-row)
    unsigned sA = (unsigned)ssrc[e0 + grp];
    unsigned sB = (unsigned)ssrc[e0 + 4 + grp];
    sA = (e0 < e1a) ? sA : (unsigned)wid;
    sB = (e0 < e1b) ? sB : (unsigned)wid;

    for (int t = e0; t < e1; t += 8) {
        float4 a = *(const float4*)(xl + (sA << 6) + cb);
        float4 b = *(const float4*)(xl + (sB << 6) + cb);
        int tn = t + 8;
        unsigned nA = (unsigned)ssrc[tn + grp];
        unsigned nB = (unsigned)ssrc[tn + 4 + grp];
        nA = (tn < e1a) ? nA : (unsigned)wid;
        nB = (tn < e1b) ? nB : (unsigned)wid;
        bool vA = t < e1a;
        bool vB = t < e1b;

        float ux = a.x + xr4.x;
        float uy = a.y + xr4.y;
        float uz = a.z + xr4.z;
        float uw = a.w + xr4.w;
        float pa = fmaf(attP.x, ux, attN.x * __builtin_fabsf(ux));
        pa = fmaf(attP.y, uy, fmaf(attN.y, __builtin_fabsf(uy), pa));
        pa = fmaf(attP.z, uz, fmaf(attN.z, __builtin_fabsf(uz), pa));
        pa = fmaf(attP.w, uw, fmaf(attN.w, __builtin_fabsf(uw), pa));
        pa = dpp_add<0xB1>(pa);
        pa = dpp_add<0x4E>(pa);
        if (L == 2) {
            pa = dpp_add<0x141>(pa);
            pa = dpp_add<0x140>(pa);
        }
        float pA = exp2f(pa);
        pA = vA ? pA : 0.f;
        s += pA;
        acc.x += pA * a.x; acc.y += pA * a.y; acc.z += pA * a.z; acc.w += pA * a.w;

        float vx = b.x + xr4.x;
        float vy = b.y + xr4.y;
        float vz = b.z + xr4.z;
        float vw = b.w + xr4.w;
        float pb = fmaf(attP.x, vx, attN.x * __builtin_fabsf(vx));
        pb = fmaf(attP.y, vy, fmaf(attN.y, __builtin_fabsf(vy), pb));
        pb = fmaf(attP.z, vz, fmaf(attN.z, __builtin_fabsf(vz), pb));
        pb = fmaf(attP.w, vw, fmaf(attN.w, __builtin_fabsf(vw), pb));
        pb = dpp_add<0xB1>(pb);
        pb = dpp_add<0x4E>(pb);
        if (L == 2) {
            pb = dpp_add<0x141>(pb);
            pb = dpp_add<0x140>(pb);
        }
        float pB = exp2f(pb);
        pB = vB ? pB : 0.f;
        s += pB;
        acc.x += pB * b.x; acc.y += pB * b.y; acc.z += pB * b.z; acc.w += pB * b.w;

        sA = nA; sB = nB;
    }

    // combine the 4 edge groups (once per node)
    s += __shfl_xor(s, 16); s += __shfl_xor(s, 32);
    acc.x += __shfl_xor(acc.x, 16); acc.x += __shfl_xor(acc.x, 32);
    acc.y += __shfl_xor(acc.y, 16); acc.y += __shfl_xor(acc.y, 32);
    acc.z += __shfl_xor(acc.z, 16); acc.z += __shfl_xor(acc.z, 32);
    acc.w += __shfl_xor(acc.w, 16); acc.w += __shfl_xor(acc.w, 32);

    float inv = 1.f / (s + 1e-16f);
    if (L == 1) {
        float4 val;
        val.x = acc.x * inv + bias4.x;
        val.y = acc.y * inv + bias4.y;
        val.z = acc.z * inv + bias4.z;
        val.w = acc.w * inv + bias4.w;
        val.x = (val.x > 0.f) ? val.x : (__expf(val.x) - 1.f);
        val.y = (val.y > 0.f) ? val.y : (__expf(val.y) - 1.f);
        val.z = (val.z > 0.f) ? val.z : (__expf(val.z) - 1.f);
        val.w = (val.w > 0.f) ? val.w : (__expf(val.w) - 1.f);
        if (grp == 0) *(float4*)(out + rb + cb) = val;
    } else {
        float4 lw = *(const float4*)(linW + cb);
        float r = (acc.x * inv + bias4.x) * lw.x + (acc.y * inv + bias4.y) * lw.y +
                  (acc.z * inv + bias4.z) * lw.z + (acc.w * inv + bias4.w) * lw.w;
        r = dpp_add<0xB1>(r);
        r = dpp_add<0x4E>(r);
        r = dpp_add<0x141>(r);
        r = dpp_add<0x140>(r);
        if (lane == 0) out[wid] = r + linb[0];
    }
}

extern "C" void kernel_launch(void* const* d_in, const int* in_sizes, int n_in,
                              void* d_out, int out_size, void* d_ws, size_t ws_size,
                              hipStream_t stream) {
    const int* x = (const int*)d_in[0];
    const int* ei = (const int*)d_in[1];          // int32 marshalled
    const float* birth_tab = (const float*)d_in[2];
    const float* gender_tab = (const float*)d_in[3];
    const float* symp_tab = (const float*)d_in[4];
    const float* Wl1 = (const float*)d_in[5];
    const float* bl1 = (const float*)d_in[6];
    const float* Wr1 = (const float*)d_in[7];
    const float* br1 = (const float*)d_in[8];
    const float* att1 = (const float*)d_in[9];
    const float* bias1 = (const float*)d_in[10];
    const float* Wl2 = (const float*)d_in[11];
    const float* bl2 = (const float*)d_in[12];
    const float* Wr2 = (const float*)d_in[13];
    const float* br2 = (const float*)d_in[14];
    const float* att2 = (const float*)d_in[15];
    const float* bias2 = (const float*)d_in[16];
    const float* linW = (const float*)d_in[17];
    const float* linb = (const float*)d_in[18];
    float* outp = (float*)d_out;

    int N = in_sizes[0] / XCOLS;   // 100000
    int E = in_sizes[1] / 2;       // 1600000
    int NB = (N + BSZ - 1) >> BSH; // 782

    char* p = (char*)d_ws;
    auto alloc = [&](size_t bytes) {
        void* r = (void*)p;
        p += (bytes + 255) & ~(size_t)255;
        return r;
    };
    float* h0 = (float*)alloc((size_t)N * EMB * 4);
    float* bufA = (float*)alloc((size_t)N * EMB * 4);
    float* bufB = (float*)alloc((size_t)N * EMB * 4);
    int* bcursor = (int*)alloc(MAXNB * 4);
    int* offs = (int*)alloc((size_t)N * 4);
    int* eoffs = (int*)alloc((size_t)N * 4);
    int* ssrc = (int*)alloc(((size_t)NB * SCAP + 256) * 4);
    float* tL = (float*)alloc((size_t)TROWS * EMB * 4);
    float* tR = (float*)alloc((size_t)TROWS * EMB * 4);
    int* epart = (int*)h0;   // alias: epart (NB*CAP = 8MB) dead before gat1 writes h0

    int ngrp = (N + 3) / 4;
    int ngrp8 = (N + 7) / 8;
    int PB = (E + PCHUNK - 1) / PCHUNK;   // 391

    transform_kernel<<<TROWS, 64, 0, stream>>>(birth_tab, gender_tab, symp_tab,
                                               Wl1, Wr1, tL, tR, bcursor);
    // partition + embedgemm run concurrently (block-role split, 512 threads)
    partition_embed_kernel<<<PB + ngrp8, 512, 0, stream>>>(ei, bcursor, epart, E, NB, PB,
                                                           x, tL, tR, bl1, br1,
                                                           bufA, bufB, N);
    finalize_kernel<<<NB, 256, 0, stream>>>(epart, bcursor, offs, eoffs, ssrc, N,
                                            NB * SCAP);

    // node pipeline
    gat_kernel<1><<<ngrp, 256, 0, stream>>>(bufA, bufB, offs, eoffs, ssrc, att1, bias1,
                                            nullptr, nullptr, h0, N);
    gemm_dual_kernel<<<768, 256, 0, stream>>>(h0, Wl2, bl2, Wr2, br2, bufA, bufB, N);
    gat_kernel<2><<<ngrp, 256, 0, stream>>>(bufA, bufB, offs, eoffs, ssrc, att2, bias2,
                                            linW, linb, outp, N);
}

// Round 26
// 198.008 us; speedup vs baseline: 1.1853x; 1.1595x over previous
//
#include <hip/hip_runtime.h>
#include <hip/hip_bf16.h>
#include <hip/hip_fp16.h>

#define EMB 64
#define XCOLS 20
#define NSYMP 15
#define BSH 7
#define BSZ 128          // nodes per bucket (1<<BSH)
#define MAXNB 1024       // supports N <= 131072
#define PCHUNK 4096
#define TROWS 51         // 4 birth + 2 gender + 45 symp rows
#define CAP 2560         // fixed edge capacity per bucket (~11 sigma margin)
#define SCAP (CAP + BSZ) // slot capacity per bucket incl. self-loops

typedef float sf16 __attribute__((ext_vector_type(16)));

// ---------------- table transform (+ zero bcursor; saves a memset dispatch) --
__global__ void transform_kernel(const float* __restrict__ bt,
                                 const float* __restrict__ gt,
                                 const float* __restrict__ st,
                                 const float* __restrict__ Wl,
                                 const float* __restrict__ Wr,
                                 float* __restrict__ tL, float* __restrict__ tR,
                                 int* __restrict__ bcursor) {
    __shared__ float row[EMB];
    int r = blockIdx.x;          // 0..50
    int d = threadIdx.x;         // 64 threads
    int gi = r * 64 + d;
    if (gi < MAXNB) bcursor[gi] = 0;
    const float* src = (r < 4) ? (bt + r * EMB)
                     : (r < 6) ? (gt + (r - 4) * EMB)
                               : (st + (r - 6) * EMB);
    row[d] = src[d];
    __syncthreads();
    float aL = 0.f, aR = 0.f;
#pragma unroll
    for (int k = 0; k < EMB; ++k) {
        float h = row[k];
        aL = fmaf(h, Wl[k * EMB + d], aL);
        aR = fmaf(h, Wr[k * EMB + d], aR);
    }
    tL[r * EMB + d] = aL;
    tR[r * EMB + d] = aR;
}

// ---------------- partition + fused embedgemm (block-role split, 512 thr) ---
// xl output now fp16 (gat's randomly-gathered operand; halves gather bytes).
__global__ void partition_embed_kernel(const int* __restrict__ ei, int* __restrict__ bcursor,
                                       int* __restrict__ epart, int E, int NB, int PB,
                                       const int* __restrict__ x,
                                       const float* __restrict__ tL,
                                       const float* __restrict__ tR,
                                       const float* __restrict__ bl,
                                       const float* __restrict__ br,
                                       __half* __restrict__ outLh,
                                       float* __restrict__ outR,
                                       int N) {
    __shared__ int lh8[8][MAXNB];  // partition role (32 KB)
    __shared__ int xs[8 * XCOLS];  // embed role (640 B)
    if (blockIdx.x >= PB) {
        // ---- embedgemm role: 8 nodes per 512-thread block ----
        int bid = blockIdx.x - PB;
        int node = bid * 8 + (threadIdx.x >> 6);
        int d = threadIdx.x & 63;
        if (threadIdx.x < 8 * XCOLS) {
            int n2 = bid * 8 + threadIdx.x / XCOLS;
            xs[threadIdx.x] = (n2 < N) ? x[(size_t)bid * 8 * XCOLS + threadIdx.x] : 0;
        }
        __syncthreads();
        if (node >= N) return;
        const int* xr = &xs[(threadIdx.x >> 6) * XCOLS];
        int rbi = xr[1] + 2 * xr[2] + 3 * xr[3];   // birth row 0..3
        int rg = 4 + xr[4];                        // gender row 4..5
        float fL = 0.f, fR = 0.f;
#pragma unroll
        for (int j = 0; j < NSYMP; ++j) {
            int row = 6 + j * 3 + xr[5 + j];
            fL += tL[row * EMB + d];
            fR += tR[row * EMB + d];
        }
        float aL = (tL[rbi * EMB + d] + tL[rg * EMB + d] + fL * (1.f / 15.f)) * (1.f / 3.f) + bl[d];
        float aR = (tR[rbi * EMB + d] + tR[rg * EMB + d] + fR * (1.f / 15.f)) * (1.f / 3.f) + br[d];
        outLh[node * EMB + d] = __float2half(aL);
        outR[node * EMB + d] = aR;
        return;
    }
    // ---- partition role ----
    int w = threadIdx.x >> 6;      // wave 0..7
    for (int j = threadIdx.x; j < 8 * MAXNB; j += 512) ((int*)lh8)[j] = 0;
    __syncthreads();
    int base = blockIdx.x * PCHUNK;
    int end = min(E, base + PCHUNK);
    for (int i = base + threadIdx.x; i < end; i += 512)
        atomicAdd(&lh8[w][ei[E + i] >> BSH], 1);
    __syncthreads();
    for (int j = threadIdx.x; j < NB; j += 512) {
        int c[8];
        int tot = 0;
#pragma unroll
        for (int k = 0; k < 8; ++k) { c[k] = lh8[k][j]; tot += c[k]; }
        int rb = tot ? (j * CAP + atomicAdd(&bcursor[j], tot)) : 0;
#pragma unroll
        for (int k = 0; k < 8; ++k) { lh8[k][j] = rb; rb += c[k]; }
    }
    __syncthreads();
    for (int i = base + threadIdx.x; i < end; i += 512) {
        int dst = ei[E + i];
        int src = ei[i];
        int slot = atomicAdd(&lh8[w][dst >> BSH], 1);
        epart[slot] = (src << BSH) | (dst & (BSZ - 1));
    }
}

// ---------------- dual GEMM v8: scalar-cache h broadcast + register weights --
// outL now fp16 (gat's gathered operand); outR fp32.
__global__ __launch_bounds__(256, 3)
void gemm_dual_kernel(const float* __restrict__ h,
                      const float* __restrict__ Wl, const float* __restrict__ bl,
                      const float* __restrict__ Wr, const float* __restrict__ br,
                      __half* __restrict__ outLh, float* __restrict__ outR, int N) {
    int lane = threadIdx.x & 63;
    int wv = threadIdx.x >> 6;
    float wl[EMB], wr[EMB];
#pragma unroll
    for (int k = 0; k < EMB; ++k) {
        wl[k] = Wl[k * EMB + lane];
        wr[k] = Wr[k * EMB + lane];
    }
    float blv = bl[lane], brv = br[lane];
    int stride = gridDim.x * 4;
    for (int node = blockIdx.x * 4 + wv; node < N; node += stride) {
        int un = __builtin_amdgcn_readfirstlane(node);
        const float* hrow = h + (size_t)un * EMB;
        sf16 va, vb, vc, vd;
        asm volatile("s_load_dwordx16 %0, %1, 0x0"  : "=s"(va) : "s"(hrow));
        asm volatile("s_load_dwordx16 %0, %1, 0x40" : "=s"(vb) : "s"(hrow));
        asm volatile("s_load_dwordx16 %0, %1, 0x80" : "=s"(vc) : "s"(hrow));
        asm volatile("s_load_dwordx16 %0, %1, 0xc0" : "=s"(vd) : "s"(hrow));
        asm volatile("s_waitcnt lgkmcnt(0)" ::: "memory");
        __builtin_amdgcn_sched_barrier(0);
        float l0 = blv, l1 = 0.f, r0 = brv, r1 = 0.f;
#pragma unroll
        for (int k = 0; k < 16; ++k) {
            l0 = fmaf(va[k], wl[k], l0);
            r0 = fmaf(va[k], wr[k], r0);
            l1 = fmaf(vb[k], wl[16 + k], l1);
            r1 = fmaf(vb[k], wr[16 + k], r1);
            l0 = fmaf(vc[k], wl[32 + k], l0);
            r0 = fmaf(vc[k], wr[32 + k], r0);
            l1 = fmaf(vd[k], wl[48 + k], l1);
            r1 = fmaf(vd[k], wr[48 + k], r1);
        }
        outLh[(size_t)node * EMB + lane] = __float2half(l0 + l1);
        outR[(size_t)node * EMB + lane] = r0 + r1;
    }
}

// finalize: bucket b's edges at epart[b*CAP .. b*CAP+cnt); slots for its 128
// nodes at ssrc[b*SCAP ..]. Writes offs (start) and eoffs (end) per node.
__global__ void finalize_kernel(const int* __restrict__ epart, const int* __restrict__ bcursor,
                                int* __restrict__ offs, int* __restrict__ eoffs,
                                int* __restrict__ ssrc, int N, int S /* pad start */) {
    __shared__ int deg4[4][BSZ];
    __shared__ int pos[BSZ];
    __shared__ int cur4[4][BSZ];
    int b = blockIdx.x;
    int t = threadIdx.x;
    int w = t >> 6;
    int n0 = b << BSH;
    int cnt = bcursor[b];
    int r0 = b * CAP, r1 = r0 + cnt;
    int sbase = b * SCAP;
    if (b == 0 && t < 128) ssrc[S + t] = 0;
    ((int*)deg4)[t] = 0;
    ((int*)deg4)[t + 256] = 0;
    __syncthreads();
    for (int e = r0 + t; e < r1; e += 256)
        atomicAdd(&deg4[w][epart[e] & (BSZ - 1)], 1);
    __syncthreads();
    int d0 = 0, d1 = 0, d2 = 0, sum = 0;
    if (t < BSZ) {
        d0 = deg4[0][t]; d1 = deg4[1][t]; d2 = deg4[2][t];
        sum = d0 + d1 + d2 + deg4[3][t];
        pos[t] = sum;
    }
    __syncthreads();
    for (int off = 1; off < BSZ; off <<= 1) {
        int v = (t < BSZ && t >= off) ? pos[t - off] : 0;
        __syncthreads();
        if (t < BSZ) pos[t] += v;
        __syncthreads();
    }
    if (t < BSZ) {
        int node = n0 + t;
        int base = sbase + (pos[t] - sum) + t;   // edges-before + self-slots-before
        if (node < N) {
            offs[node] = base;
            eoffs[node] = base + 1 + sum;        // end of this node's range
            ssrc[base] = node;                   // self-loop at slot 0
        }
        cur4[0][t] = base + 1;
        cur4[1][t] = base + 1 + d0;
        cur4[2][t] = base + 1 + d0 + d1;
        cur4[3][t] = base + 1 + d0 + d1 + d2;
    }
    __syncthreads();
    for (int e = r0 + t; e < r1; e += 256) {
        int v = epart[e];
        int s = atomicAdd(&cur4[w][v & (BSZ - 1)], 1);
        ssrc[s] = v >> BSH;
    }
}

// ---------------- DPP cross-lane add (VALU pipe; compiler handles hazards) --
template <int CTRL>
__device__ __forceinline__ float dpp_add(float v) {
    union { float f; int i; } u, r;
    u.f = v;
    r.i = __builtin_amdgcn_update_dpp(0, u.i, CTRL, 0xF, 0xF, true);
    return v + r.f;
}

__device__ __forceinline__ float4 half4_to_float4(float2 raw) {
    const __half2* h = (const __half2*)&raw;
    float2 f01 = __half22float2(h[0]);
    float2 f23 = __half22float2(h[1]);
    float4 r;
    r.x = f01.x; r.y = f01.y; r.z = f23.x; r.w = f23.y;
    return r;
}

// ---------------- GATv2 layer: 8 edges per wave iteration, pipelined --------
// R26: xl gathered as fp16 (8B/lane, halves the random-gather stream which
// R25 showed is gat's binding constraint); cvt cost paid from leaky-fold's
// freed VALU slack. xr/acc/outputs stay fp32. R17 clamp retained.
template <int L>
__global__ void gat_kernel(const __half* __restrict__ xl, const float* __restrict__ xr,
                           const int* __restrict__ offs, const int* __restrict__ eoffs,
                           const int* __restrict__ ssrc,
                           const float* __restrict__ att, const float* __restrict__ bias,
                           const float* __restrict__ linW, const float* __restrict__ linb,
                           float* __restrict__ out, int N) {
    int wid = blockIdx.x * 4 + (threadIdx.x >> 6);
    int lane = threadIdx.x & 63;
    if (wid >= N) return;
    int grp = lane >> 4;          // edge slot within the 4-wide half-batch
    int li = lane & 15;           // float4 channel slot
    unsigned cb = (unsigned)li << 2;

    const float LOG2E = 1.4426950408889634f;
    float4 att4 = *(const float4*)(att + cb);
    float4 attP, attN;
    attP.x = att4.x * (0.6f * LOG2E); attN.x = att4.x * (0.4f * LOG2E);
    attP.y = att4.y * (0.6f * LOG2E); attN.y = att4.y * (0.4f * LOG2E);
    attP.z = att4.z * (0.6f * LOG2E); attN.z = att4.z * (0.4f * LOG2E);
    attP.w = att4.w * (0.6f * LOG2E); attN.w = att4.w * (0.4f * LOG2E);
    float4 bias4 = *(const float4*)(bias + cb);
    unsigned rb = (unsigned)wid << 6;
    float4 xr4 = *(const float4*)(xr + rb + cb);

    int e0 = offs[wid], e1 = eoffs[wid];
    int e1a = e1 - grp;           // t+grp < e1    <=>  t < e1a
    int e1b = e1 - 4 - grp;       // t+4+grp < e1  <=>  t < e1b

    float s = 0.f;
    float4 acc = {0.f, 0.f, 0.f, 0.f};

    // prologue (allocated pad -> unconditional loads OK; clamp to hot own-row)
    unsigned sA = (unsigned)ssrc[e0 + grp];
    unsigned sB = (unsigned)ssrc[e0 + 4 + grp];
    sA = (e0 < e1a) ? sA : (unsigned)wid;
    sB = (e0 < e1b) ? sB : (unsigned)wid;

    for (int t = e0; t < e1; t += 8) {
        float2 rawA = *(const float2*)(xl + ((sA << 6) | cb));
        float2 rawB = *(const float2*)(xl + ((sB << 6) | cb));
        int tn = t + 8;
        unsigned nA = (unsigned)ssrc[tn + grp];
        unsigned nB = (unsigned)ssrc[tn + 4 + grp];
        nA = (tn < e1a) ? nA : (unsigned)wid;
        nB = (tn < e1b) ? nB : (unsigned)wid;
        bool vA = t < e1a;
        bool vB = t < e1b;

        float4 a = half4_to_float4(rawA);
        float ux = a.x + xr4.x;
        float uy = a.y + xr4.y;
        float uz = a.z + xr4.z;
        float uw = a.w + xr4.w;
        float pa = fmaf(attP.x, ux, attN.x * __builtin_fabsf(ux));
        pa = fmaf(attP.y, uy, fmaf(attN.y, __builtin_fabsf(uy), pa));
        pa = fmaf(attP.z, uz, fmaf(attN.z, __builtin_fabsf(uz), pa));
        pa = fmaf(attP.w, uw, fmaf(attN.w, __builtin_fabsf(uw), pa));
        pa = dpp_add<0xB1>(pa);
        pa = dpp_add<0x4E>(pa);
        if (L == 2) {
            pa = dpp_add<0x141>(pa);
            pa = dpp_add<0x140>(pa);
        }
        float pA = exp2f(pa);
        pA = vA ? pA : 0.f;
        s += pA;
        acc.x += pA * a.x; acc.y += pA * a.y; acc.z += pA * a.z; acc.w += pA * a.w;

        float4 b = half4_to_float4(rawB);
        float vx = b.x + xr4.x;
        float vy = b.y + xr4.y;
        float vz = b.z + xr4.z;
        float vw = b.w + xr4.w;
        float pb = fmaf(attP.x, vx, attN.x * __builtin_fabsf(vx));
        pb = fmaf(attP.y, vy, fmaf(attN.y, __builtin_fabsf(vy), pb));
        pb = fmaf(attP.z, vz, fmaf(attN.z, __builtin_fabsf(vz), pb));
        pb = fmaf(attP.w, vw, fmaf(attN.w, __builtin_fabsf(vw), pb));
        pb = dpp_add<0xB1>(pb);
        pb = dpp_add<0x4E>(pb);
        if (L == 2) {
            pb = dpp_add<0x141>(pb);
            pb = dpp_add<0x140>(pb);
        }
        float pB = exp2f(pb);
        pB = vB ? pB : 0.f;
        s += pB;
        acc.x += pB * b.x; acc.y += pB * b.y; acc.z += pB * b.z; acc.w += pB * b.w;

        sA = nA; sB = nB;
    }

    // combine the 4 edge groups (once per node)
    s += __shfl_xor(s, 16); s += __shfl_xor(s, 32);
    acc.x += __shfl_xor(acc.x, 16); acc.x += __shfl_xor(acc.x, 32);
    acc.y += __shfl_xor(acc.y, 16); acc.y += __shfl_xor(acc.y, 32);
    acc.z += __shfl_xor(acc.z, 16); acc.z += __shfl_xor(acc.z, 32);
    acc.w += __shfl_xor(acc.w, 16); acc.w += __shfl_xor(acc.w, 32);

    float inv = 1.f / (s + 1e-16f);
    if (L == 1) {
        float4 val;
        val.x = acc.x * inv + bias4.x;
        val.y = acc.y * inv + bias4.y;
        val.z = acc.z * inv + bias4.z;
        val.w = acc.w * inv + bias4.w;
        val.x = (val.x > 0.f) ? val.x : (__expf(val.x) - 1.f);
        val.y = (val.y > 0.f) ? val.y : (__expf(val.y) - 1.f);
        val.z = (val.z > 0.f) ? val.z : (__expf(val.z) - 1.f);
        val.w = (val.w > 0.f) ? val.w : (__expf(val.w) - 1.f);
        if (grp == 0) *(float4*)(out + rb + cb) = val;
    } else {
        float4 lw = *(const float4*)(linW + cb);
        float r = (acc.x * inv + bias4.x) * lw.x + (acc.y * inv + bias4.y) * lw.y +
                  (acc.z * inv + bias4.z) * lw.z + (acc.w * inv + bias4.w) * lw.w;
        r = dpp_add<0xB1>(r);
        r = dpp_add<0x4E>(r);
        r = dpp_add<0x141>(r);
        r = dpp_add<0x140>(r);
        if (lane == 0) out[wid] = r + linb[0];
    }
}

extern "C" void kernel_launch(void* const* d_in, const int* in_sizes, int n_in,
                              void* d_out, int out_size, void* d_ws, size_t ws_size,
                              hipStream_t stream) {
    const int* x = (const int*)d_in[0];
    const int* ei = (const int*)d_in[1];          // int32 marshalled
    const float* birth_tab = (const float*)d_in[2];
    const float* gender_tab = (const float*)d_in[3];
    const float* symp_tab = (const float*)d_in[4];
    const float* Wl1 = (const float*)d_in[5];
    const float* bl1 = (const float*)d_in[6];
    const float* Wr1 = (const float*)d_in[7];
    const float* br1 = (const float*)d_in[8];
    const float* att1 = (const float*)d_in[9];
    const float* bias1 = (const float*)d_in[10];
    const float* Wl2 = (const float*)d_in[11];
    const float* bl2 = (const float*)d_in[12];
    const float* Wr2 = (const float*)d_in[13];
    const float* br2 = (const float*)d_in[14];
    const float* att2 = (const float*)d_in[15];
    const float* bias2 = (const float*)d_in[16];
    const float* linW = (const float*)d_in[17];
    const float* linb = (const float*)d_in[18];
    float* outp = (float*)d_out;

    int N = in_sizes[0] / XCOLS;   // 100000
    int E = in_sizes[1] / 2;       // 1600000
    int NB = (N + BSZ - 1) >> BSH; // 782

    char* p = (char*)d_ws;
    auto alloc = [&](size_t bytes) {
        void* r = (void*)p;
        p += (bytes + 255) & ~(size_t)255;
        return r;
    };
    float* h0 = (float*)alloc((size_t)N * EMB * 4);
    __half* xh = (__half*)alloc((size_t)N * EMB * 2 + 256);  // fp16 xl (+pad)
    float* bufB = (float*)alloc((size_t)N * EMB * 4);
    int* bcursor = (int*)alloc(MAXNB * 4);
    int* offs = (int*)alloc((size_t)N * 4);
    int* eoffs = (int*)alloc((size_t)N * 4);
    int* ssrc = (int*)alloc(((size_t)NB * SCAP + 256) * 4);
    float* tL = (float*)alloc((size_t)TROWS * EMB * 4);
    float* tR = (float*)alloc((size_t)TROWS * EMB * 4);
    int* epart = (int*)h0;   // alias: epart (NB*CAP = 8MB) dead before gat1 writes h0

    int ngrp = (N + 3) / 4;
    int ngrp8 = (N + 7) / 8;
    int PB = (E + PCHUNK - 1) / PCHUNK;   // 391

    transform_kernel<<<TROWS, 64, 0, stream>>>(birth_tab, gender_tab, symp_tab,
                                               Wl1, Wr1, tL, tR, bcursor);
    // partition + embedgemm run concurrently (block-role split, 512 threads)
    partition_embed_kernel<<<PB + ngrp8, 512, 0, stream>>>(ei, bcursor, epart, E, NB, PB,
                                                           x, tL, tR, bl1, br1,
                                                           xh, bufB, N);
    finalize_kernel<<<NB, 256, 0, stream>>>(epart, bcursor, offs, eoffs, ssrc, N,
                                            NB * SCAP);

    // node pipeline
    gat_kernel<1><<<ngrp, 256, 0, stream>>>(xh, bufB, offs, eoffs, ssrc, att1, bias1,
                                            nullptr, nullptr, h0, N);
    gemm_dual_kernel<<<768, 256, 0, stream>>>(h0, Wl2, bl2, Wr2, br2, xh, bufB, N);
    gat_kernel<2><<<ngrp, 256, 0, stream>>>(xh, bufB, offs, eoffs, ssrc, att2, bias2,
                                            linW, linb, outp, N);
}